// Round 1
// baseline (886.842 us; speedup 1.0000x reference)
//
#include <hip/hip_runtime.h>
#include <math.h>

#define F 128
#define R 16
#define O 12
#define NB 32   // nodes per block in fused MLP

// ---------------- small utility kernels ----------------
__global__ void zero_int_kernel(int* __restrict__ p, int n) {
    int i = blockIdx.x * blockDim.x + threadIdx.x;
    if (i < n) p[i] = 0;
}

// ---------------- CSR build: histogram ----------------
__global__ __launch_bounds__(256) void hist_kernel(
    const int* __restrict__ idx, int* __restrict__ cnt, int E)
{
    int i = blockIdx.x * blockDim.x + threadIdx.x;
    int stride = gridDim.x * blockDim.x;
    for (; i < E; i += stride) atomicAdd(&cnt[idx[i]], 1);
}

// ---------------- CSR build: exclusive scan (single block) ----------------
__global__ __launch_bounds__(1024) void scan_kernel(
    const int* __restrict__ cnt, int* __restrict__ off,
    int* __restrict__ cur, int N, int E)
{
    __shared__ int part[1024];
    int t = threadIdx.x;
    const int per = (N + 1023) / 1024;
    int s0 = t * per;
    int s = 0;
    for (int i = 0; i < per; i++) { int k = s0 + i; if (k < N) s += cnt[k]; }
    part[t] = s;
    __syncthreads();
    for (int d = 1; d < 1024; d <<= 1) {
        int v = (t >= d) ? part[t - d] : 0;
        __syncthreads();
        part[t] += v;
        __syncthreads();
    }
    int run = (t == 0) ? 0 : part[t - 1];
    for (int i = 0; i < per; i++) {
        int k = s0 + i;
        if (k < N) { off[k] = run; cur[k] = run; run += cnt[k]; }
    }
    if (t == 0) off[N] = E;
}

// ---------------- CSR build: fill edge lists ----------------
__global__ __launch_bounds__(256) void fill_kernel(
    const int* __restrict__ idx, int* __restrict__ cur,
    int* __restrict__ csr, int E)
{
    int i = blockIdx.x * blockDim.x + threadIdx.x;
    int stride = gridDim.x * blockDim.x;
    for (; i < E; i += stride) {
        int n = idx[i];
        int p = atomicAdd(&cur[n], 1);
        csr[p] = i;
    }
}

__device__ __forceinline__ float dot16(const float4* r, const float4* Wv) {
    float s = 0.f;
    #pragma unroll
    for (int q = 0; q < 4; q++)
        s += r[q].x * Wv[q].x + r[q].y * Wv[q].y + r[q].z * Wv[q].z + r[q].w * Wv[q].w;
    return s;
}

// ---------------- fused rbf-linear * gate -> GATHER (no atomics) ----------------
// v3: TWO waves per node (each takes half the edge list, LDS combine) to
// double concurrent latency chains; __launch_bounds__(256,4) raises VGPR cap
// to 128 so all 20 data loads of a 4-edge batch stay live (v2 compiled to 76
// VGPR = compiler re-serialized to ~2 edges in flight); sched_barrier(0)
// pins the load cluster above the math; next batch's csr indices prefetched
// during current compute to break the csr->data serial chain.
__global__ __launch_bounds__(256, 4) void gather_kernel(
    const float* __restrict__ m, const float* __restrict__ rbf,
    const int* __restrict__ csr, const int* __restrict__ off,
    const float* __restrict__ Wrbf, float* __restrict__ A, int N)
{
    __shared__ float part[2 * F];    // partials from the "half==1" waves
    const int lane = threadIdx.x & 63;
    const int w    = threadIdx.x >> 6;   // 0..3
    const int ln   = w >> 1;             // local node 0..1
    const int half = w & 1;              // which half of the edge list
    const int n = blockIdx.x * 2 + ln;
    const bool active = (n < N);

    const int f0 = lane << 1;
    float4 W0[4], W1[4];
    #pragma unroll
    for (int q = 0; q < 4; q++) {
        W0[q] = *(const float4*)(Wrbf + (size_t)f0 * R + q * 4);
        W1[q] = *(const float4*)(Wrbf + (size_t)(f0 + 1) * R + q * 4);
    }

    float a0 = 0.f, a1 = 0.f;

    if (active) {
        const int jb = off[n], je = off[n + 1];
        const int cnt = je - jb;
        const int c0 = (cnt >> 1) & ~3;          // multiple of 4, <= cnt/2
        int j       = half ? (jb + c0) : jb;
        const int e = half ? je        : (jb + c0);

        if (j + 4 <= e) {
            int e0 = csr[j], e1 = csr[j + 1], e2 = csr[j + 2], e3 = csr[j + 3];
            while (j + 4 <= e) {
                const int jn = j + 4;
                const int jp = (jn + 4 <= e) ? jn : j;   // clamp: re-read cur (L1 hit)
                int p0 = csr[jp], p1 = csr[jp + 1], p2 = csr[jp + 2], p3 = csr[jp + 3];

                float2 m0 = *(const float2*)(m + (size_t)e0 * F + f0);
                float2 m1 = *(const float2*)(m + (size_t)e1 * F + f0);
                float2 m2 = *(const float2*)(m + (size_t)e2 * F + f0);
                float2 m3 = *(const float2*)(m + (size_t)e3 * F + f0);
                float4 r0[4], r1[4], r2[4], r3[4];
                #pragma unroll
                for (int q = 0; q < 4; q++) {
                    r0[q] = ((const float4*)(rbf + (size_t)e0 * R))[q];
                    r1[q] = ((const float4*)(rbf + (size_t)e1 * R))[q];
                    r2[q] = ((const float4*)(rbf + (size_t)e2 * R))[q];
                    r3[q] = ((const float4*)(rbf + (size_t)e3 * R))[q];
                }
                // All 24 VMEM ops (4 csr prefetch + 4 m + 16 rbf) must be in
                // flight before the first vmcnt wait — forbid re-serialization.
                __builtin_amdgcn_sched_barrier(0);
                a0 += dot16(r0, W0) * m0.x;  a1 += dot16(r0, W1) * m0.y;
                a0 += dot16(r1, W0) * m1.x;  a1 += dot16(r1, W1) * m1.y;
                a0 += dot16(r2, W0) * m2.x;  a1 += dot16(r2, W1) * m2.y;
                a0 += dot16(r3, W0) * m3.x;  a1 += dot16(r3, W1) * m3.y;
                e0 = p0; e1 = p1; e2 = p2; e3 = p3;
                j = jn;
            }
        }
        for (; j < e; j++) {             // scalar tail (only the half==1 wave)
            const int e0 = csr[j];
            float2 m0 = *(const float2*)(m + (size_t)e0 * F + f0);
            float4 r0[4];
            #pragma unroll
            for (int q = 0; q < 4; q++)
                r0[q] = ((const float4*)(rbf + (size_t)e0 * R))[q];
            a0 += dot16(r0, W0) * m0.x;
            a1 += dot16(r0, W1) * m0.y;
        }
    }

    if (half == 1) {                     // float2-stride writes: 2-way bank alias = free
        part[ln * F + f0]     = a0;
        part[ln * F + f0 + 1] = a1;
    }
    __syncthreads();
    if (active && half == 0) {
        a0 += part[ln * F + f0];
        a1 += part[ln * F + f0 + 1];
        *(float2*)(A + (size_t)n * F + f0) = make_float2(a0, a1);
    }
}

// ---------------- fused MLP (3 layers) + projection ----------------
// 32 nodes per block, 625 blocks. Weights staged per layer into 64KB LDS;
// activations in 16KB LDS updated IN-PLACE (rows are wave-local -> no
// inter-layer sync needed). 80KB LDS -> 2 blocks/CU.
__global__ __launch_bounds__(256) void mlp_fused(
    const float* __restrict__ A, const float* __restrict__ dW,
    const float* __restrict__ db, const float* __restrict__ Wout,
    float* __restrict__ out, int N)
{
    __shared__ float Ws[F * F];     // 64 KB
    __shared__ float act[NB * F];   // 16 KB
    int t = threadIdx.x;
    int base = blockIdx.x * NB;
    int j = t & 15, i = t >> 4;

    int  n0[2]; bool ok[2];
    #pragma unroll
    for (int k = 0; k < 2; k++) { n0[k] = base + i + 16 * k; ok[k] = n0[k] < N; }

    for (int l = 0; l < 3; l++) {
        __syncthreads();
        for (int s = t; s < F * F / 4; s += 256) {
            int g = s >> 5, c = s & 31;
            float4 v = *(const float4*)(dW + (size_t)l * F * F + g * F + (c << 2));
            *(float4*)(Ws + g * F + ((c ^ (g & 31)) << 2)) = v;
        }
        __syncthreads();

        float acc[2][8];
        #pragma unroll
        for (int k = 0; k < 2; k++)
            #pragma unroll
            for (int mm = 0; mm < 8; mm++) acc[k][mm] = 0.f;

        for (int c = 0; c < 32; c++) {
            int f = c << 2;
            float4 av[2];
            #pragma unroll
            for (int k = 0; k < 2; k++) {
                if (l == 0)
                    av[k] = ok[k] ? *(const float4*)(A + (size_t)n0[k] * F + f)
                                  : make_float4(0.f, 0.f, 0.f, 0.f);
                else
                    av[k] = *(const float4*)(act + (i + 16 * k) * F + f);
            }
            float4 wv[8];
            #pragma unroll
            for (int mm = 0; mm < 8; mm++) {
                int g = j + 16 * mm;
                wv[mm] = *(const float4*)(Ws + g * F + ((c ^ (g & 31)) << 2));
            }
            #pragma unroll
            for (int k = 0; k < 2; k++)
                #pragma unroll
                for (int mm = 0; mm < 8; mm++)
                    acc[k][mm] += av[k].x * wv[mm].x + av[k].y * wv[mm].y +
                                  av[k].z * wv[mm].z + av[k].w * wv[mm].w;
        }

        #pragma unroll
        for (int mm = 0; mm < 8; mm++) {
            int g = j + 16 * mm;
            float bias = db[l * F + g];
            #pragma unroll
            for (int k = 0; k < 2; k++) {
                float x = acc[k][mm] + bias;
                act[(i + 16 * k) * F + g] = x / (1.f + __expf(-x));
            }
        }
    }

    // ---- projection ----
    __syncthreads();
    for (int s = t; s < O * F / 4; s += 256)
        ((float4*)Ws)[s] = ((const float4*)Wout)[s];
    __syncthreads();

    int nl = t >> 3;                 // 0..31
    int oq = t & 7;
    int n = base + nl;
    if (n < N) {
        float s0 = 0.f, s1 = 0.f;
        for (int f = 0; f < F; f += 4) {
            float4 a  = *(const float4*)(act + nl * F + f);
            float4 w0 = *(const float4*)(Ws + oq * F + f);
            s0 += a.x * w0.x + a.y * w0.y + a.z * w0.z + a.w * w0.w;
            if (oq < 4) {
                float4 w1 = *(const float4*)(Ws + (8 + oq) * F + f);
                s1 += a.x * w1.x + a.y * w1.y + a.z * w1.z + a.w * w1.w;
            }
        }
        out[(size_t)n * O + oq] = s0;
        if (oq < 4) out[(size_t)n * O + 8 + oq] = s1;
    }
}

extern "C" void kernel_launch(void* const* d_in, const int* in_sizes, int n_in,
                              void* d_out, int out_size, void* d_ws, size_t ws_size,
                              hipStream_t stream)
{
    const float* m    = (const float*)d_in[0];
    const float* rbf  = (const float*)d_in[1];
    const int*   aei  = (const int*)d_in[2];
    const float* Wrbf = (const float*)d_in[3];
    const float* dW   = (const float*)d_in[4];
    const float* db   = (const float*)d_in[5];
    const float* Wout = (const float*)d_in[6];
    float* out = (float*)d_out;

    int E = in_sizes[0] / F;     // 640000
    int N = out_size / O;        // 20000

    float* A = (float*)d_ws;
    int* csr = (int*)(A + (size_t)N * F);
    int* cnt = csr + E;
    int* cur = cnt + N;
    int* off = cur + N;

    const int* idx1 = aei + E;   // row 1 = receiving atoms

    zero_int_kernel<<<(N + 255) / 256, 256, 0, stream>>>(cnt, N);
    hist_kernel<<<1024, 256, 0, stream>>>(idx1, cnt, E);
    scan_kernel<<<1, 1024, 0, stream>>>(cnt, off, cur, N, E);
    fill_kernel<<<1024, 256, 0, stream>>>(idx1, cur, csr, E);
    gather_kernel<<<(N + 1) / 2, 256, 0, stream>>>(m, rbf, csr, off, Wrbf, A, N);

    mlp_fused<<<(N + NB - 1) / NB, 256, 0, stream>>>(A, dW, db, Wout, out, N);
}

// Round 2
// 743.366 us; speedup vs baseline: 1.1930x; 1.1930x over previous
//
#include <hip/hip_runtime.h>
#include <math.h>

#define F 128
#define R 16
#define O 12
#define NB 32   // nodes per block in fused MLP
#define EB 16   // edges per staging batch in gather

// ---------------- small utility kernels ----------------
__global__ void zero_int_kernel(int* __restrict__ p, int n) {
    int i = blockIdx.x * blockDim.x + threadIdx.x;
    if (i < n) p[i] = 0;
}

// ---------------- CSR build: histogram ----------------
__global__ __launch_bounds__(256) void hist_kernel(
    const int* __restrict__ idx, int* __restrict__ cnt, int E)
{
    int i = blockIdx.x * blockDim.x + threadIdx.x;
    int stride = gridDim.x * blockDim.x;
    for (; i < E; i += stride) atomicAdd(&cnt[idx[i]], 1);
}

// ---------------- CSR build: exclusive scan (single block) ----------------
__global__ __launch_bounds__(1024) void scan_kernel(
    const int* __restrict__ cnt, int* __restrict__ off,
    int* __restrict__ cur, int N, int E)
{
    __shared__ int part[1024];
    int t = threadIdx.x;
    const int per = (N + 1023) / 1024;
    int s0 = t * per;
    int s = 0;
    for (int i = 0; i < per; i++) { int k = s0 + i; if (k < N) s += cnt[k]; }
    part[t] = s;
    __syncthreads();
    for (int d = 1; d < 1024; d <<= 1) {
        int v = (t >= d) ? part[t - d] : 0;
        __syncthreads();
        part[t] += v;
        __syncthreads();
    }
    int run = (t == 0) ? 0 : part[t - 1];
    for (int i = 0; i < per; i++) {
        int k = s0 + i;
        if (k < N) { off[k] = run; cur[k] = run; run += cnt[k]; }
    }
    if (t == 0) off[N] = E;
}

// ---------------- CSR build: fill edge lists ----------------
__global__ __launch_bounds__(256) void fill_kernel(
    const int* __restrict__ idx, int* __restrict__ cur,
    int* __restrict__ csr, int E)
{
    int i = blockIdx.x * blockDim.x + threadIdx.x;
    int stride = gridDim.x * blockDim.x;
    for (; i < E; i += stride) {
        int n = idx[i];
        int p = atomicAdd(&cur[n], 1);
        csr[p] = i;
    }
}

__device__ __forceinline__ float dot16(const float4* r, const float4* Wv) {
    float s = 0.f;
    #pragma unroll
    for (int q = 0; q < 4; q++)
        s += r[q].x * Wv[q].x + r[q].y * Wv[q].y + r[q].z * Wv[q].z + r[q].w * Wv[q].w;
    return s;
}

// direct global->LDS DMA: per-lane global src, wave-uniform LDS base + lane*16
__device__ __forceinline__ void gld_lds16(const float* g, float* l) {
    __builtin_amdgcn_global_load_lds(
        (const __attribute__((address_space(1))) void*)g,
        (__attribute__((address_space(3))) void*)l,
        16, 0, 0);
}

// ---------------- fused rbf-linear * gate -> GATHER (no atomics) ----------------
// v4: stage edge data via global_load_lds (in-flight bytes tracked by vmcnt,
// ~0 VGPR cost -> no spill risk, v3's failure mode). One wave per node.
// Batch EB=16 edges: 8 insts stage 16 m-rows (lanes 0-31 row 2k, lanes 32-63
// row 2k+1: per-lane global addr, linear LDS dest = HW requirement), 1 inst
// stages all 16 rbf rows (lane -> row lane>>2, byte (lane&3)*16).
// 9.2 KB in flight per wave; 36 KB LDS/block -> 4 blocks/CU -> 16 waves/CU.
__global__ __launch_bounds__(256) void gather_kernel(
    const float* __restrict__ m, const float* __restrict__ rbf,
    const int* __restrict__ csr, const int* __restrict__ off,
    const float* __restrict__ Wrbf, float* __restrict__ A, int N)
{
    __shared__ float m_buf[4 * EB * F];    // 32 KB (8 KB per wave)
    __shared__ float r_buf[4 * EB * R];    // 4 KB  (1 KB per wave)
    const int lane = threadIdx.x & 63;
    const int w = threadIdx.x >> 6;
    const int n = blockIdx.x * 4 + w;
    if (n >= N) return;

    float* mw = m_buf + w * EB * F;        // wave-uniform LDS bases
    float* rw = r_buf + w * EB * R;

    const int f0 = lane << 1;
    float4 W0[4], W1[4];
    #pragma unroll
    for (int q = 0; q < 4; q++) {
        W0[q] = *(const float4*)(Wrbf + (size_t)f0 * R + q * 4);
        W1[q] = *(const float4*)(Wrbf + (size_t)(f0 + 1) * R + q * 4);
    }

    float a0 = 0.f, a1 = 0.f;
    const int jb = off[n], je = off[n + 1];

    for (int j = jb; j < je; j += EB) {
        const int c = (je - j < EB) ? (je - j) : EB;

        // prior batch's ds_reads must be complete before DMA overwrites LDS
        asm volatile("s_waitcnt lgkmcnt(0)" ::: "memory");

        #pragma unroll
        for (int k = 0; k < EB / 2; k++) {
            if (2 * k < c) {                       // wave-uniform branch
                int jj = j + 2 * k + (lane >> 5);  // lanes 0-31: row 2k; 32-63: row 2k+1
                if (jj > je - 1) jj = je - 1;      // clamp (dup load, rows >= c unread)
                int e = csr[jj];
                gld_lds16(m + (size_t)e * F + ((lane & 31) << 2), mw + k * 2 * F);
            }
        }
        {
            int jj = j + (lane >> 2);              // 16 rbf rows in one inst
            if (jj > je - 1) jj = je - 1;
            int e = csr[jj];
            gld_lds16(rbf + (size_t)e * R + ((lane & 3) << 2), rw);
        }

        asm volatile("s_waitcnt vmcnt(0)" ::: "memory");

        for (int r = 0; r < c; r++) {
            float2 mv = *(const float2*)(mw + r * F + f0);    // 8B/lane: conflict-free
            const float4* rr = (const float4*)(rw + r * R);   // uniform: broadcast
            float4 rv[4] = { rr[0], rr[1], rr[2], rr[3] };
            a0 += dot16(rv, W0) * mv.x;
            a1 += dot16(rv, W1) * mv.y;
        }
    }

    *(float2*)(A + (size_t)n * F + f0) = make_float2(a0, a1);
}

// ---------------- fused MLP (3 layers) + projection ----------------
// 32 nodes per block, 625 blocks. Weights staged per layer into 64KB LDS;
// activations in 16KB LDS updated IN-PLACE (rows are wave-local -> no
// inter-layer sync needed). 80KB LDS -> 2 blocks/CU.
__global__ __launch_bounds__(256) void mlp_fused(
    const float* __restrict__ A, const float* __restrict__ dW,
    const float* __restrict__ db, const float* __restrict__ Wout,
    float* __restrict__ out, int N)
{
    __shared__ float Ws[F * F];     // 64 KB
    __shared__ float act[NB * F];   // 16 KB
    int t = threadIdx.x;
    int base = blockIdx.x * NB;
    int j = t & 15, i = t >> 4;

    int  n0[2]; bool ok[2];
    #pragma unroll
    for (int k = 0; k < 2; k++) { n0[k] = base + i + 16 * k; ok[k] = n0[k] < N; }

    for (int l = 0; l < 3; l++) {
        __syncthreads();
        for (int s = t; s < F * F / 4; s += 256) {
            int g = s >> 5, c = s & 31;
            float4 v = *(const float4*)(dW + (size_t)l * F * F + g * F + (c << 2));
            *(float4*)(Ws + g * F + ((c ^ (g & 31)) << 2)) = v;
        }
        __syncthreads();

        float acc[2][8];
        #pragma unroll
        for (int k = 0; k < 2; k++)
            #pragma unroll
            for (int mm = 0; mm < 8; mm++) acc[k][mm] = 0.f;

        for (int c = 0; c < 32; c++) {
            int f = c << 2;
            float4 av[2];
            #pragma unroll
            for (int k = 0; k < 2; k++) {
                if (l == 0)
                    av[k] = ok[k] ? *(const float4*)(A + (size_t)n0[k] * F + f)
                                  : make_float4(0.f, 0.f, 0.f, 0.f);
                else
                    av[k] = *(const float4*)(act + (i + 16 * k) * F + f);
            }
            float4 wv[8];
            #pragma unroll
            for (int mm = 0; mm < 8; mm++) {
                int g = j + 16 * mm;
                wv[mm] = *(const float4*)(Ws + g * F + ((c ^ (g & 31)) << 2));
            }
            #pragma unroll
            for (int k = 0; k < 2; k++)
                #pragma unroll
                for (int mm = 0; mm < 8; mm++)
                    acc[k][mm] += av[k].x * wv[mm].x + av[k].y * wv[mm].y +
                                  av[k].z * wv[mm].z + av[k].w * wv[mm].w;
        }

        #pragma unroll
        for (int mm = 0; mm < 8; mm++) {
            int g = j + 16 * mm;
            float bias = db[l * F + g];
            #pragma unroll
            for (int k = 0; k < 2; k++) {
                float x = acc[k][mm] + bias;
                act[(i + 16 * k) * F + g] = x / (1.f + __expf(-x));
            }
        }
    }

    // ---- projection ----
    __syncthreads();
    for (int s = t; s < O * F / 4; s += 256)
        ((float4*)Ws)[s] = ((const float4*)Wout)[s];
    __syncthreads();

    int nl = t >> 3;                 // 0..31
    int oq = t & 7;
    int n = base + nl;
    if (n < N) {
        float s0 = 0.f, s1 = 0.f;
        for (int f = 0; f < F; f += 4) {
            float4 a  = *(const float4*)(act + nl * F + f);
            float4 w0 = *(const float4*)(Ws + oq * F + f);
            s0 += a.x * w0.x + a.y * w0.y + a.z * w0.z + a.w * w0.w;
            if (oq < 4) {
                float4 w1 = *(const float4*)(Ws + (8 + oq) * F + f);
                s1 += a.x * w1.x + a.y * w1.y + a.z * w1.z + a.w * w1.w;
            }
        }
        out[(size_t)n * O + oq] = s0;
        if (oq < 4) out[(size_t)n * O + 8 + oq] = s1;
    }
}

extern "C" void kernel_launch(void* const* d_in, const int* in_sizes, int n_in,
                              void* d_out, int out_size, void* d_ws, size_t ws_size,
                              hipStream_t stream)
{
    const float* m    = (const float*)d_in[0];
    const float* rbf  = (const float*)d_in[1];
    const int*   aei  = (const int*)d_in[2];
    const float* Wrbf = (const float*)d_in[3];
    const float* dW   = (const float*)d_in[4];
    const float* db   = (const float*)d_in[5];
    const float* Wout = (const float*)d_in[6];
    float* out = (float*)d_out;

    int E = in_sizes[0] / F;     // 640000
    int N = out_size / O;        // 20000

    float* A = (float*)d_ws;
    int* csr = (int*)(A + (size_t)N * F);
    int* cnt = csr + E;
    int* cur = cnt + N;
    int* off = cur + N;

    const int* idx1 = aei + E;   // row 1 = receiving atoms

    zero_int_kernel<<<(N + 255) / 256, 256, 0, stream>>>(cnt, N);
    hist_kernel<<<1024, 256, 0, stream>>>(idx1, cnt, E);
    scan_kernel<<<1, 1024, 0, stream>>>(cnt, off, cur, N, E);
    fill_kernel<<<1024, 256, 0, stream>>>(idx1, cur, csr, E);
    gather_kernel<<<(N + 3) / 4, 256, 0, stream>>>(m, rbf, csr, off, Wrbf, A, N);

    mlp_fused<<<(N + NB - 1) / NB, 256, 0, stream>>>(A, dW, db, Wout, out, N);
}